// Round 6
// baseline (1019.419 us; speedup 1.0000x reference)
//
#include <hip/hip_runtime.h>

// SparseConv3d(32->64, k=3, s=2, p=1), (21,800,704) grid, nnz=220939.
// Round 10: dense-map gather, restructured into bulk phases.
//   r9 post-mortem: per-hit serial chain (wave-uniform global feat load +
//   vmcnt(0) inside a dynamic do-while) + per-k weight reloads left waves
//   stalled ~99% -> 546us. FETCH model validated (118MB map traffic).
//   r10: block = 128 sites. Phase 1: 27x128 probes as 14 independent
//   coalesced rounds -> block-local rulebook in LDS. Phase 2: counting
//   sort by k. Phase 3: stage ALL hit feat rows coalesced into LDS
//   (XOR-swizzled). Phase 4: wave w owns k-stripe {w,w+4,..}; weights
//   double-buffer-prefetched; inner loop = broadcast ds_read + pk_fma +
//   ds_add only. Tile stored once, coalesced (covers zeroing).
//   Overflow/dup paths: exact global-atomic fixups (statistically ~never
//   for overflow, ~2K dups).

#define CIN    32
#define COUT   64
#define IXD    21
#define IYD    800
#define IZD    704
#define OXD    11
#define OYD    400
#define OZD    352
#define NOUT   (OXD * OYD * OZD)        // 1,548,800
#define NVOX   (IXD * IYD * IZD)        // 11,827,200
#define NVOX4  (NVOX / 4)               // 2,956,800 (exact)
#define BSITES 128
#define NBLK   (NOUT / BSITES)          // 12,100 (exact)
#define NWT    (27 * COUT * CIN)        // 55,296 floats
#define CAP    256                      // hits per block (avg ~62, max ~101)

typedef float v2f __attribute__((ext_vector_type(2)));

// ---------------------------------------------------------------- prep ----
__global__ __launch_bounds__(256) void prep(const float* __restrict__ w,
                                            int4* __restrict__ map4,
                                            float* __restrict__ wt,
                                            int* __restrict__ dupcnt,
                                            int* __restrict__ ovcnt) {
    const int i = blockIdx.x * 256 + threadIdx.x;
    if (i < NVOX4) map4[i] = make_int4(-1, -1, -1, -1);
    if (i < NWT) {
        const int k  = i >> 11;          // 2048 = 64*32 per offset
        const int rm = i & 2047;
        const int co = rm >> 5;
        const int ci = rm & 31;
        wt[i] = w[k * (CIN * COUT) + ci * COUT + co];   // WT[k][co][ci]
    }
    if (i == 0) { *dupcnt = 0; *ovcnt = 0; }
}

// ----------------------------------------------------------- build_map ----
__global__ __launch_bounds__(256) void build_map(
    const int* __restrict__ coords,
    int* __restrict__ map,
    int* __restrict__ dupcnt,
    int* __restrict__ duplist,
    int dupcap, int nnz)
{
    const int n = blockIdx.x * 256 + threadIdx.x;
    if (n >= nnz) return;
    const int cx = coords[3 * n + 0];
    const int cy = coords[3 * n + 1];
    const int cz = coords[3 * n + 2];
    const int v  = (cx * IYD + cy) * IZD + cz;
    const int old = atomicExch(&map[v], n);
    if (old >= 0) {                       // displaced point: handle in fixup
        const int s = atomicAdd(dupcnt, 1);
        if (s < dupcap) duplist[s] = old;
    }
}

// -------------------------------------------------------------- gather ----
__global__ __launch_bounds__(256, 3) void spconv_gather(
    const float* __restrict__ feat,
    const float* __restrict__ wt,
    const int*   __restrict__ map,
    float*       __restrict__ out,
    int*         __restrict__ ovcnt,
    int2*        __restrict__ ovlist,
    int ovcap)
{
    __shared__ float tile[BSITES][COUT];    // 32 KB == output tile
    __shared__ float fstage[BSITES][CIN];   // 16 KB: staged feat rows
    __shared__ int   hraw[CAP];
    __shared__ int   sorted[CAP];
    __shared__ int   khist[27];
    __shared__ int   kbase[27];
    __shared__ int   hcnt;

    const int t    = threadIdx.x;
    const int lane = t & 63;
    const int wid  = t >> 6;

    if (t < 27) khist[t] = 0;
    if (t == 0) hcnt = 0;
    float4* t4 = (float4*)&tile[0][0];
    #pragma unroll
    for (int r = 0; r < 8; ++r) t4[t + r * 256] = make_float4(0.f, 0.f, 0.f, 0.f);
    __syncthreads();

    // ---- phase 1: 27x128 probes, 14 independent coalesced rounds ----
    // thread t handles (k = 2r + (t>>7), loc = t&127): site fixed per thread.
    const int loc  = t & 127;
    const int kh   = t >> 7;
    const int site = blockIdx.x * BSITES + loc;
    const int ox   = site / (OYD * OZD);
    const int rr0  = site - ox * (OYD * OZD);
    const int oy   = rr0 / OZD;
    const int oz   = rr0 - oy * OZD;
    const int ix0  = 2 * ox - 1, iy0 = 2 * oy - 1, iz0 = 2 * oz - 1;

    for (int r = 0; r < 14; ++r) {
        const int k = 2 * r + kh;
        if (k >= 27) break;
        const int kx = k / 9, kr2 = k - 9 * kx;
        const int ky = kr2 / 3, kz = kr2 - 3 * ky;
        const int ix = ix0 + kx, iy = iy0 + ky, iz = iz0 + kz;
        int p = -1;
        if ((unsigned)ix < IXD && (unsigned)iy < IYD && (unsigned)iz < IZD)
            p = map[(ix * IYD + iy) * IZD + iz];
        if (p >= 0) {
            const int pos = atomicAdd(&hcnt, 1);
            if (pos < CAP) {
                hraw[pos] = (p << 12) | (k << 7) | loc;
                atomicAdd(&khist[k], 1);
            } else {                      // ~never: exact fallback
                const int o = atomicAdd(ovcnt, 1);
                if (o < ovcap) ovlist[o] = make_int2(site, (p << 5) | k);
            }
        }
    }
    __syncthreads();

    // ---- phase 2: exclusive scan of 27 bins (wave 0) ----
    if (wid == 0) {
        const int h = (lane < 27) ? khist[lane] : 0;
        int v = h;
        #pragma unroll
        for (int off = 1; off < 32; off <<= 1) {
            const int u = __shfl_up(v, off);
            if (lane >= off) v += u;
        }
        if (lane < 27) kbase[lane] = v - h;
    }
    __syncthreads();

    const int cnt = min(hcnt, CAP);
    for (int i = t; i < cnt; i += 256) {
        const int wd = hraw[i];
        const int k  = (wd >> 7) & 31;
        const int pos = atomicAdd(&kbase[k], 1);
        sorted[pos] = wd;
    }
    __syncthreads();        // sorted ready; kbase[k] = END of run k

    // ---- phases 3+4 per group of <=128 hits (usually exactly one) ----
    for (int g0 = 0; g0 < cnt; g0 += BSITES) {
        const int gn = min(BSITES, cnt - g0);

        // issue first weight buffer early: hides under staging
        float4 wv0[8], wv1[8];
        {
            const float4* __restrict__ wp =
                (const float4*)(wt + ((size_t)wid * COUT + lane) * CIN);
            #pragma unroll
            for (int b = 0; b < 8; ++b) wv0[b] = wp[b];
        }

        // stage feat rows [g0, g0+gn): 8 lanes per row, XOR-swizzled chunks
        for (int q = t >> 3; q < gn; q += 32) {
            const int p  = sorted[g0 + q] >> 12;
            const int ch = t & 7;
            ((float4*)&fstage[q][0])[ch ^ (q & 7)] =
                ((const float4*)(feat + (size_t)p * CIN))[ch];
        }
        __syncthreads();

        // compute: wave wid owns k-stripe {wid, wid+4, ...}; dbuf weights
        #pragma unroll
        for (int s = 0; s < 7; ++s) {
            const int k  = wid + 4 * s;
            float4* wv = (s & 1) ? wv1 : wv0;
            float4* wn = (s & 1) ? wv0 : wv1;
            const int kn = k + 4;
            if (s < 6 && kn < 27) {       // prefetch next stripe-k weights
                const float4* __restrict__ wp =
                    (const float4*)(wt + ((size_t)kn * COUT + lane) * CIN);
                #pragma unroll
                for (int b = 0; b < 8; ++b) wn[b] = wp[b];
            }
            if (k < 27) {
                const int jlo = max((k == 0) ? 0 : kbase[k - 1], g0);
                const int jhi = min(kbase[k], g0 + gn);
                for (int j = jlo; j < jhi; ++j) {
                    const int wd  = sorted[j];          // broadcast
                    const int l2  = wd & 127;
                    const int row = j - g0;
                    v2f a0 = {0.f, 0.f}, a1 = {0.f, 0.f};
                    #pragma unroll
                    for (int b = 0; b < 8; ++b) {
                        const float4 f =
                            ((const float4*)&fstage[row][0])[b ^ (row & 7)];
                        const float4 wb = wv[b];
                        v2f f01 = {f.x, f.y}, f23 = {f.z, f.w};
                        v2f w01 = {wb.x, wb.y}, w23 = {wb.z, wb.w};
#if __has_builtin(__builtin_elementwise_fma)
                        a0 = __builtin_elementwise_fma(f01, w01, a0);
                        a1 = __builtin_elementwise_fma(f23, w23, a1);
#else
                        a0[0] = fmaf(f01[0], w01[0], a0[0]);
                        a0[1] = fmaf(f01[1], w01[1], a0[1]);
                        a1[0] = fmaf(f23[0], w23[0], a1[0]);
                        a1[1] = fmaf(f23[1], w23[1], a1[1]);
#endif
                    }
                    atomicAdd(&tile[l2][lane],
                              (a0[0] + a0[1]) + (a1[0] + a1[1]));   // ds_add
                }
            }
        }
        __syncthreads();
    }

    // single coalesced 32KB store — write-once output, zeroing included
    float4* __restrict__ o4 = (float4*)(out + (size_t)blockIdx.x * (BSITES * COUT));
    #pragma unroll
    for (int r = 0; r < 8; ++r) o4[t + r * 256] = t4[t + r * 256];
}

// --------------------------------------------------------- fixup_pairs ----
__global__ __launch_bounds__(256) void fixup_pairs(
    const float* __restrict__ feat,
    const float* __restrict__ wt,
    const int2*  __restrict__ ovlist,
    const int*   __restrict__ ovcnt,
    int ovcap,
    float*       __restrict__ out)
{
    const int lane = threadIdx.x & 63;
    const int gw   = blockIdx.x * 4 + (threadIdx.x >> 6);
    const int n    = min(*ovcnt, ovcap);
    for (int e = gw; e < n; e += 32 * 4) {
        const int2 r   = ovlist[e];
        const int site = r.x;
        const int p    = r.y >> 5;
        const int k    = r.y & 31;
        const float4* __restrict__ wp =
            (const float4*)(wt + ((size_t)k * COUT + lane) * CIN);
        const float4* __restrict__ fp = (const float4*)(feat + (size_t)p * CIN);
        float acc = 0.f;
        #pragma unroll
        for (int b = 0; b < 8; ++b) {
            const float4 f = fp[b];
            const float4 w = wp[b];
            acc = fmaf(f.x, w.x, acc);
            acc = fmaf(f.y, w.y, acc);
            acc = fmaf(f.z, w.z, acc);
            acc = fmaf(f.w, w.w, acc);
        }
        atomicAdd(out + (size_t)site * COUT + lane, acc);
    }
}

// ---------------------------------------------------------- fixup_dups ----
__global__ __launch_bounds__(256) void fixup_dups(
    const float* __restrict__ feat,
    const float* __restrict__ wt,
    const int*   __restrict__ coords,
    const int*   __restrict__ duplist,
    const int*   __restrict__ dupcnt,
    int dupcap,
    float*       __restrict__ out)
{
    const int lane = threadIdx.x & 63;
    const int gw   = blockIdx.x * 4 + (threadIdx.x >> 6);
    const int n    = min(*dupcnt, dupcap);
    for (int e = gw; e < n; e += 64 * 4) {
        const int p  = duplist[e];
        const int cx = coords[3 * p + 0];
        const int cy = coords[3 * p + 1];
        const int cz = coords[3 * p + 2];
        int kxl[2], oxl[2], nx;
        int kyl[2], oyl[2], ny;
        int kzl[2], ozl[2], nz;
        {
            const int c1 = cx + 1;
            if (c1 & 1) { kxl[0] = 1; oxl[0] = c1 >> 1; nx = 1; }
            else { kxl[0] = 2; oxl[0] = (c1 - 2) >> 1; nx = 1;
                   if ((c1 >> 1) < OXD) { kxl[1] = 0; oxl[1] = c1 >> 1; nx = 2; } }
        }
        {
            const int c1 = cy + 1;
            if (c1 & 1) { kyl[0] = 1; oyl[0] = c1 >> 1; ny = 1; }
            else { kyl[0] = 2; oyl[0] = (c1 - 2) >> 1; ny = 1;
                   if ((c1 >> 1) < OYD) { kyl[1] = 0; oyl[1] = c1 >> 1; ny = 2; } }
        }
        {
            const int c1 = cz + 1;
            if (c1 & 1) { kzl[0] = 1; ozl[0] = c1 >> 1; nz = 1; }
            else { kzl[0] = 2; ozl[0] = (c1 - 2) >> 1; nz = 1;
                   if ((c1 >> 1) < OZD) { kzl[1] = 0; ozl[1] = c1 >> 1; nz = 2; } }
        }
        const float4* __restrict__ fp = (const float4*)(feat + (size_t)p * CIN);
        float4 fr[8];
        #pragma unroll
        for (int b = 0; b < 8; ++b) fr[b] = fp[b];
        for (int ix = 0; ix < nx; ++ix)
            for (int iy = 0; iy < ny; ++iy)
                for (int iz = 0; iz < nz; ++iz) {
                    const int k    = kxl[ix] * 9 + kyl[iy] * 3 + kzl[iz];
                    const int site = (oxl[ix] * OYD + oyl[iy]) * OZD + ozl[iz];
                    const float4* __restrict__ wp =
                        (const float4*)(wt + ((size_t)k * COUT + lane) * CIN);
                    float acc = 0.f;
                    #pragma unroll
                    for (int b = 0; b < 8; ++b) {
                        const float4 f = fr[b];
                        const float4 w = wp[b];
                        acc = fmaf(f.x, w.x, acc);
                        acc = fmaf(f.y, w.y, acc);
                        acc = fmaf(f.z, w.z, acc);
                        acc = fmaf(f.w, w.w, acc);
                    }
                    atomicAdd(out + (size_t)site * COUT + lane, acc);
                }
    }
}

// -------------------------------------------------------------- launch ----
extern "C" void kernel_launch(void* const* d_in, const int* in_sizes, int n_in,
                              void* d_out, int out_size, void* d_ws, size_t ws_size,
                              hipStream_t stream) {
    const float* feat   = (const float*)d_in[0];
    const int*   coords = (const int*)d_in[1];
    const float* weight = (const float*)d_in[2];
    float*       out    = (float*)d_out;
    const int nnz = in_sizes[0] / CIN;            // 220939

    // workspace: map (47.31MB) | WT (216KB) | counters | duplist | ovlist
    int*   map     = (int*)d_ws;
    float* WT      = (float*)(map + NVOX);
    int*   dupcnt  = (int*)(WT + NWT);
    int*   ovcnt   = dupcnt + 4;
    int*   duplist = ovcnt + 4;
    const size_t fixed = (size_t)((char*)duplist - (char*)d_ws);
    long avail = (long)ws_size - (long)fixed - 64;
    int cap = (int)(avail / 12);                  // dupcap ints + ovcap int2
    if (cap > 48000) cap = 48000;
    if (cap < 1024)  cap = 1024;
    const int dupcap = cap & ~1;
    const int ovcap  = cap;
    int2* ovlist = (int2*)(duplist + dupcap);

    prep<<<(NVOX4 + 255) / 256, 256, 0, stream>>>(weight, (int4*)map, WT,
                                                  dupcnt, ovcnt);
    build_map<<<(nnz + 255) / 256, 256, 0, stream>>>(coords, map, dupcnt,
                                                     duplist, dupcap, nnz);
    spconv_gather<<<NBLK, 256, 0, stream>>>(feat, WT, map, out,
                                            ovcnt, ovlist, ovcap);
    fixup_pairs<<<32, 256, 0, stream>>>(feat, WT, ovlist, ovcnt, ovcap, out);
    fixup_dups<<<64, 256, 0, stream>>>(feat, WT, coords, duplist, dupcnt,
                                       dupcap, out);
}

// Round 7
// 801.497 us; speedup vs baseline: 1.2719x; 1.2719x over previous
//
#include <hip/hip_runtime.h>

// SparseConv3d(32->64, k=3, s=2, p=1), (21,800,704) grid, nnz=220939.
// Round 11: two-phase k-major GEMM -> bucket reduce (r7 revived; ws is
// ~1.59GB per the harness poison-fill evidence, so the 130MB fast path fits).
//   r10 post-mortem: phased gather spilled weight dbuf to scratch
//   (+613MB HBM traffic, VGPR=84); short per-k runs force either reload
//   latency or register pressure. Fix: k-major phase A where weights are
//   WAVE-UNIFORM -> streamed through the SCALAR pipe (s_loads, SGPRs),
//   lane = pair, feat row in VGPRs, zero LDS, no atomics:
//     gemm_k  : per pair 16 v_pk_fma instrs + 8 coalesced-row fp16 stores.
//   Phase B: per bucket, per pair ONE coalesced 128B fp16 P-row load +
//   ds_add_f32 into a 32KB tile; single write-once tile store (zeroing).
//   Build: LDS-aggregated kcnt + 64B-padded bucket counters; pair word
//   packs prow=(k*pcapk+slotk) so reduce needs no decode. Overflow ->
//   exact recompute fixup (expected empty at pcapk=32768).

#define CIN    32
#define COUT   64
#define OXD    11
#define OYD    400
#define OZD    352
#define NOUT   (OXD * OYD * OZD)      // 1,548,800
#define BSITES 128
#define NBUCK  (NOUT / BSITES)        // 12,100
#define CAP    256                    // pairs per bucket (avg ~62, max ~120)
#define GSTR   16                     // bcnt stride: 1 counter per 64B line
#define NWT    (27 * COUT * CIN)      // 55,296 floats
#define CHA    32                     // chunks per k in phase A
#define PCAPK_MAX 32768               // > max per-k count (~28.9K)
#define OVCAP  600000

typedef float v2f __attribute__((ext_vector_type(2)));
typedef _Float16 half_t;
typedef _Float16 h8 __attribute__((ext_vector_type(8)));

// ---------------------------------------------------------------- prep ----
__global__ __launch_bounds__(256) void prep(const float* __restrict__ w,
                                            float* __restrict__ wt,
                                            int* __restrict__ kcnt,
                                            int* __restrict__ bcnt,
                                            int* __restrict__ ovcnt) {
    const int i = blockIdx.x * 256 + threadIdx.x;
    if (i < NWT) {
        const int k  = i >> 11;          // 2048 = 64*32 per offset
        const int rm = i & 2047;
        const int co = rm >> 5;
        const int ci = rm & 31;
        wt[i] = w[k * (CIN * COUT) + ci * COUT + co];   // WT[k][co][ci]
    }
    if (i < NBUCK) bcnt[i * GSTR] = 0;
    if (i < 32)    kcnt[i] = 0;
    if (i == 0)    *ovcnt = 0;
}

// --------------------------------------------------------------- build ----
__global__ __launch_bounds__(512) void build_pairs(
    const int* __restrict__ coords,
    int* __restrict__ arenaA,        // [27][pcapk] point ids (k-major)
    int* __restrict__ arenaB,        // [NBUCK][CAP] packed (prow<<7)|loc
    int* __restrict__ kcnt,
    int* __restrict__ bcnt,
    int* __restrict__ ovcnt,
    int2* __restrict__ ovlist,
    int nnz, int pcapk)
{
    __shared__ int lcnt[27];
    __shared__ int lbase[27];
    const int t = threadIdx.x;
    if (t < 27) lcnt[t] = 0;
    __syncthreads();

    const int n = blockIdx.x * 512 + t;
    int ncomb = 0;
    int ck[8], cls[8], csite[8];
    if (n < nnz) {
        const int cx = coords[3 * n + 0];
        const int cy = coords[3 * n + 1];
        const int cz = coords[3 * n + 2];
        int kxl[2], oxl[2], nx;
        int kyl[2], oyl[2], ny;
        int kzl[2], ozl[2], nz;
        {
            const int c1 = cx + 1;
            if (c1 & 1) { kxl[0] = 1; oxl[0] = c1 >> 1; nx = 1; }
            else { kxl[0] = 2; oxl[0] = (c1 - 2) >> 1; nx = 1;
                   if ((c1 >> 1) < OXD) { kxl[1] = 0; oxl[1] = c1 >> 1; nx = 2; } }
        }
        {
            const int c1 = cy + 1;
            if (c1 & 1) { kyl[0] = 1; oyl[0] = c1 >> 1; ny = 1; }
            else { kyl[0] = 2; oyl[0] = (c1 - 2) >> 1; ny = 1;
                   if ((c1 >> 1) < OYD) { kyl[1] = 0; oyl[1] = c1 >> 1; ny = 2; } }
        }
        {
            const int c1 = cz + 1;
            if (c1 & 1) { kzl[0] = 1; ozl[0] = c1 >> 1; nz = 1; }
            else { kzl[0] = 2; ozl[0] = (c1 - 2) >> 1; nz = 1;
                   if ((c1 >> 1) < OZD) { kzl[1] = 0; ozl[1] = c1 >> 1; nz = 2; } }
        }
        for (int ix = 0; ix < nx; ++ix)
            for (int iy = 0; iy < ny; ++iy)
                for (int iz = 0; iz < nz; ++iz) {
                    const int k = kxl[ix] * 9 + kyl[iy] * 3 + kzl[iz];
                    ck[ncomb]    = k;
                    csite[ncomb] = (oxl[ix] * OYD + oyl[iy]) * OZD + ozl[iz];
                    cls[ncomb]   = atomicAdd(&lcnt[k], 1);
                    ++ncomb;
                }
    }
    __syncthreads();
    if (t < 27) lbase[t] = atomicAdd(&kcnt[t], lcnt[t]);
    __syncthreads();

    for (int c = 0; c < ncomb; ++c) {
        const int k     = ck[c];
        const int site  = csite[c];
        const int slotk = lbase[k] + cls[c];
        if (slotk < pcapk) {
            arenaA[(size_t)k * pcapk + slotk] = n;
            const int bkt = site >> 7;
            const int loc = site & (BSITES - 1);
            const int sb  = atomicAdd(&bcnt[bkt * GSTR], 1);
            if (sb < CAP) {
                arenaB[(size_t)bkt * CAP + sb] = ((k * pcapk + slotk) << 7) | loc;
            } else {
                const int o = atomicAdd(ovcnt, 1);
                if (o < OVCAP) ovlist[o] = make_int2(site, (n << 5) | k);
            }
        } else {
            const int o = atomicAdd(ovcnt, 1);
            if (o < OVCAP) ovlist[o] = make_int2(site, (n << 5) | k);
        }
    }
}

// ------------------------------------------- phase A: k-major GEMM ----
// lane = pair. Feat row in 32 VGPRs (direct global loads). Weights are
// wave-uniform (k, loop indices uniform) -> compiler streams them through
// SGPRs / the scalar pipe. No LDS, no atomics. Output fp16 row per pair.
__global__ __launch_bounds__(256, 3) void gemm_k(
    const float* __restrict__ feat,
    const float* __restrict__ wt,
    const int*   __restrict__ arenaA,
    const int*   __restrict__ kcnt,
    half_t*      __restrict__ P16,
    int pcapk)
{
    const int lane = threadIdx.x & 63;
    const int wid  = threadIdx.x >> 6;
    const int k     = blockIdx.x % 27;
    const int chunk = blockIdx.x / 27;
    const int cnt = min(kcnt[k], pcapk);
    if (cnt == 0) return;

    const int NW    = CHA * 4;
    const int widk  = chunk * 4 + wid;
    const int C     = (cnt + NW - 1) / NW;
    const int start = min(widk * C, cnt);
    const int end   = min(start + C, cnt);
    const float* __restrict__ Wk = wt + (size_t)k * (COUT * CIN);  // [co][ci]
    const int*   __restrict__ ak = arenaA + (size_t)k * pcapk;
    half_t*      __restrict__ Pk = P16 + (size_t)k * pcapk * COUT;

    for (int i0 = start; i0 < end; i0 += 64) {
        const int idx = i0 + lane;
        const int pt  = ak[min(idx, end - 1)];       // coalesced

        // my pair's feat row -> 16 v2f (8 independent dwordx4)
        v2f f[16];
        {
            const float4* __restrict__ fr4 = (const float4*)(feat + (size_t)pt * CIN);
            #pragma unroll
            for (int b = 0; b < 8; ++b) {
                const float4 v = fr4[b];
                f[2 * b + 0] = (v2f){v.x, v.y};
                f[2 * b + 1] = (v2f){v.z, v.w};
            }
        }

        if (idx < end) {
            half_t* __restrict__ prow = Pk + (size_t)idx * COUT;
            #pragma unroll
            for (int g = 0; g < 8; ++g) {            // 8 couts per group
                h8 res;
                #pragma unroll
                for (int u = 0; u < 8; ++u) {
                    const int co = 8 * g + u;
                    const v2f* __restrict__ wv = (const v2f*)(Wk + co * CIN);
                    v2f a = {0.f, 0.f};
                    #pragma unroll
                    for (int c2 = 0; c2 < 16; ++c2) {
#if __has_builtin(__builtin_elementwise_fma)
                        a = __builtin_elementwise_fma(f[c2], wv[c2], a);
#else
                        a[0] = fmaf(f[c2][0], wv[c2][0], a[0]);
                        a[1] = fmaf(f[c2][1], wv[c2][1], a[1]);
#endif
                    }
                    res[u] = (half_t)(a[0] + a[1]);
                }
                *(h8*)(prow + 8 * g) = res;          // 16B store
            }
        }
    }
}

// ------------------------------------------------ phase B: site reduce ----
__global__ __launch_bounds__(256, 4) void reduce_b(
    const half_t* __restrict__ P16,
    const int*    __restrict__ arenaB,
    const int*    __restrict__ bcnt,
    float*        __restrict__ out)
{
    __shared__ float tile[BSITES][COUT];   // 32 KB == output tile

    const int t    = threadIdx.x;
    const int lane = t & 63;
    const int wid  = t >> 6;
    const int b    = blockIdx.x;
    const int cnt  = min(bcnt[b * GSTR], CAP);

    float4* t4 = (float4*)&tile[0][0];
    #pragma unroll
    for (int r = 0; r < 8; ++r) t4[t + r * 256] = make_float4(0.f, 0.f, 0.f, 0.f);
    __syncthreads();

    // wave chunk of the bucket's pairs; pair words preloaded to lane regs
    const int c  = (cnt + 3) >> 2;         // <= 64
    const int jb = min(wid * c, cnt);
    const int je = min(jb + c, cnt);
    const int* __restrict__ ab = arenaB + (size_t)b * CAP;
    const int myw = ab[(jb + lane < je) ? (jb + lane) : (je > jb ? je - 1 : 0)];

    #pragma unroll 8
    for (int j = jb; j < je; ++j) {
        const int w    = __builtin_amdgcn_readlane(myw, j - jb);  // uniform
        const int prow = w >> 7;
        const int loc  = w & (BSITES - 1);
        const float h  = (float)P16[(size_t)prow * COUT + lane];  // 128B row
        atomicAdd(&tile[loc][lane], h);                           // ds_add_f32
    }
    __syncthreads();

    // single coalesced write of the whole tile — covers zeroing too
    float4* __restrict__ o4 = (float4*)(out + (size_t)b * (BSITES * COUT));
    #pragma unroll
    for (int r = 0; r < 8; ++r) o4[t + r * 256] = t4[t + r * 256];
}

// --------------------------------------------------------------- fixup ----
__global__ __launch_bounds__(256) void fixup_overflow(
    const float* __restrict__ feat,
    const float* __restrict__ wt,
    const int2*  __restrict__ ovlist,
    const int*   __restrict__ ovcnt,
    float*       __restrict__ out)
{
    const int lane = threadIdx.x & 63;
    const int gw   = blockIdx.x * 4 + (threadIdx.x >> 6);
    const int n    = min(*ovcnt, OVCAP);
    for (int e = gw; e < n; e += 64 * 4) {
        const int2 r   = ovlist[e];
        const int site = r.x;
        const int p    = r.y >> 5;
        const int k    = r.y & 31;
        const float4* __restrict__ wp =
            (const float4*)(wt + ((size_t)k * COUT + lane) * CIN);
        const float4* __restrict__ fp = (const float4*)(feat + (size_t)p * CIN);
        float acc = 0.f;
        #pragma unroll
        for (int b = 0; b < 8; ++b) {
            const float4 f = fp[b];
            const float4 w = wp[b];
            acc = fmaf(f.x, w.x, acc);
            acc = fmaf(f.y, w.y, acc);
            acc = fmaf(f.z, w.z, acc);
            acc = fmaf(f.w, w.w, acc);
        }
        atomicAdd(out + (size_t)site * COUT + lane, acc);
    }
}

// -------------------------------------------------------------- launch ----
extern "C" void kernel_launch(void* const* d_in, const int* in_sizes, int n_in,
                              void* d_out, int out_size, void* d_ws, size_t ws_size,
                              hipStream_t stream) {
    const float* feat   = (const float*)d_in[0];
    const int*   coords = (const int*)d_in[1];
    const float* weight = (const float*)d_in[2];
    float*       out    = (float*)d_out;
    const int nnz = in_sizes[0] / CIN;            // 220939

    // workspace: WT | kcnt | bcnt(padded) | ovcnt | arenaB | ovlist |
    //            arenaA[27*pcapk] | P16[27*pcapk*64] (fp16)
    float* WT     = (float*)d_ws;                           // NWT
    int*   kcnt   = (int*)(WT + NWT);                       // 32
    int*   bcnt   = kcnt + 32;                              // NBUCK*GSTR
    int*   ovcnt  = bcnt + NBUCK * GSTR;                    // 1 (+3 pad)
    int*   arenaB = ovcnt + 4;                              // NBUCK*CAP
    int2*  ovlist = (int2*)(arenaB + (size_t)NBUCK * CAP);  // OVCAP
    int*   arenaA = (int*)(ovlist + OVCAP);
    const size_t fixed = (size_t)((char*)arenaA - (char*)d_ws);

    // per pcapk unit: 27 * (4B arenaA + 64*2B P row) = 27*132 bytes
    long avail = (long)ws_size - (long)fixed - 512;
    int pcapk = (int)(avail / (27L * (sizeof(int) + COUT * sizeof(half_t))));
    if (pcapk > PCAPK_MAX) pcapk = PCAPK_MAX;
    if (pcapk < 1024)      pcapk = 1024;        // degrade via ovlist/fixup
    uintptr_t pa = (uintptr_t)(arenaA + (size_t)27 * pcapk);
    pa = (pa + 255) & ~(uintptr_t)255;          // 128B-aligned P rows
    half_t* P16 = (half_t*)pa;

    prep<<<(NWT + 255) / 256, 256, 0, stream>>>(weight, WT, kcnt, bcnt, ovcnt);
    build_pairs<<<(nnz + 511) / 512, 512, 0, stream>>>(coords, arenaA, arenaB,
                                                       kcnt, bcnt, ovcnt,
                                                       ovlist, nnz, pcapk);
    gemm_k<<<27 * CHA, 256, 0, stream>>>(feat, WT, arenaA, kcnt, P16, pcapk);
    reduce_b<<<NBUCK, 256, 0, stream>>>(P16, arenaB, bcnt, out);
    fixup_overflow<<<64, 256, 0, stream>>>(feat, WT, ovlist, ovcnt, out);
}